// Round 12
// baseline (835.912 us; speedup 1.0000x reference)
//
#include <hip/hip_runtime.h>
#include <math.h>

#define NEGV (-1e9f)

typedef _Float16 half8 __attribute__((ext_vector_type(8)));
typedef float f32x4 __attribute__((ext_vector_type(4)));

// Shapes: BS=2048, L=100, D=256, N=16, K=32
// K1: BM=256 -> 800 blocks x 512 thr (8 waves, wr 0..3 x wc 0..1).
// Wave tile 64 rows x 128 e; 3-product f16-split MFMA (hh, hm, mh).
// Same r6-winner barrier discipline (issue-early + plain __syncthreads);
// 2x work per barrier/staging vs r6, and 4 waves/SIMD occupancy.
// Epilogue: two 128-row passes; tanh -> Pj -> logits MFMA vs Cf.
// K2: r11 measured config (94us), unchanged.

__device__ inline float tanh_fast(float x) {
    float t = __expf(2.0f * x);
    float r = __builtin_amdgcn_rcpf(t + 1.0f);
    return fmaf(-2.0f, r, 1.0f);
}

__device__ inline void split8(const float4 a, const float4 b, half8& h, half8& m) {
    const float* pa = (const float*)&a;
    const float* pb = (const float*)&b;
    #pragma unroll
    for (int q = 0; q < 4; ++q) {
        float x = pa[q];
        _Float16 hi = (_Float16)x;
        h[q] = hi; m[q] = (_Float16)(x - (float)hi);
    }
    #pragma unroll
    for (int q = 0; q < 4; ++q) {
        float x = pb[q];
        _Float16 hi = (_Float16)x;
        h[4+q] = hi; m[4+q] = (_Float16)(x - (float)hi);
    }
}

__device__ inline void gload_lds16(const void* g, void* lds) {
    __builtin_amdgcn_global_load_lds(
        (const __attribute__((address_space(1))) unsigned int*)g,
        (__attribute__((address_space(3))) unsigned int*)lds, 16, 0, 0);
}

// Pre-split W into MFMA frag layout: Wf[((kt*2+spl)*16+ct)*64+lane] (half8)
//   e = ct*16+(lane&15), k-octet g = lane>>4, k = kt*32 + g*8 + j
// Pre-split cc into Cf[((et*2+spl)*2+ct)*64+lane] (half8)
//   k' = ct*16+(lane&15), e = et*32 + (lane>>4)*8 + j
__global__ __launch_bounds__(256)
void k_prep(const float* __restrict__ W, const float* __restrict__ cc,
            half8* __restrict__ Wf, half8* __restrict__ Cf)
{
    int slot = blockIdx.x * 256 + threadIdx.x;   // 9216 slots
    if (slot < 8192) {
        int kt = slot >> 10;
        int ct = (slot >> 6) & 15;
        int lane = slot & 63;
        int e = ct * 16 + (lane & 15);
        int g = lane >> 4;
        const float* src = &W[(size_t)e * 256 + kt * 32 + g * 8];
        float4 a = *(const float4*)src;
        float4 b = *(const float4*)(src + 4);
        half8 h, m;
        split8(a, b, h, m);
        Wf[((kt * 2 + 0) * 16 + ct) * 64 + lane] = h;
        Wf[((kt * 2 + 1) * 16 + ct) * 64 + lane] = m;
    } else if (slot < 9216) {
        int s = slot - 8192;
        int lane = s & 63;
        int ct = (s >> 6) & 1;
        int et = s >> 7;            // 0..7
        int k2 = ct * 16 + (lane & 15);
        int g = lane >> 4;
        const float* src = &cc[(size_t)k2 * 256 + et * 32 + g * 8];
        float4 a = *(const float4*)src;
        float4 b = *(const float4*)(src + 4);
        half8 h, m;
        split8(a, b, h, m);
        Cf[((et * 2 + 0) * 2 + ct) * 64 + lane] = h;
        Cf[((et * 2 + 1) * 2 + ct) * 64 + lane] = m;
    }
}

__global__ __launch_bounds__(512, 4)
void k_proj_logits(const float* __restrict__ hist, const half8* __restrict__ Wf,
                   const half8* __restrict__ Cf, float* __restrict__ logits)
{
    // smem: two 32KB B-frag buffers (double-buffered k-tiles);
    // epilogue aliases smem as Pj float[128][68] (34816 B, per 128-row pass)
    __shared__ __align__(16) char smem[65536];
    float (*Pj)[68] = (float(*)[68])smem;

    const int tid  = threadIdx.x;
    const int lane = tid & 63;
    const int w    = tid >> 6;       // wave 0..7
    const int wr   = w >> 1, wc = w & 1;
    const int g    = lane >> 4;      // k-octet 0..3
    const int r    = lane & 15;      // row/col within 16-tile
    const size_t rowBase = (size_t)blockIdx.x * 256;

    f32x4 acc[4][8];
    #pragma unroll
    for (int i = 0; i < 4; ++i)
        #pragma unroll
        for (int j = 0; j < 8; ++j) acc[i][j] = (f32x4)(0.0f);

    // A source: lane (r,g) reads hist[row][g*8..+7] — directly the A-frag slice
    const float* aPtr = &hist[(rowBase + (size_t)wr * 64 + r) * 256 + g * 8];
    const char*  wsrc = (const char*)Wf + tid * 16;
    const int    ldsW = (tid & 448) * 16;   // wave-uniform part of lds dest

    float4 a0[4], a1[4];
    #pragma unroll
    for (int rt = 0; rt < 4; ++rt) {
        const float* s = aPtr + rt * (16 * 256);
        a0[rt] = *(const float4*)s;
        a1[rt] = *(const float4*)(s + 4);
    }
    // stage B tile 0 into buf 0 (512 thr x 4 x 16B = 32KB)
    #pragma unroll
    for (int i = 0; i < 4; ++i)
        gload_lds16(wsrc + i * 8192, smem + ldsW + i * 8192);
    __syncthreads();   // drains vmcnt: buf0 + A(0) ready

    #pragma unroll 2
    for (int kt = 0; kt < 8; ++kt) {
        const int cur = kt & 1;
        // issue next B-tile stage EARLY (overlap with MFMA below)
        if (kt < 7) {
            const char* s = wsrc + (size_t)(kt + 1) * 32768;
            char* d = smem + (cur ^ 1) * 32768 + ldsW;
            #pragma unroll
            for (int i = 0; i < 4; ++i)
                gload_lds16(s + i * 8192, d + i * 8192);
        }
        // split A for current tile (regs loaded last iteration)
        half8 Ah[4], Am[4];
        #pragma unroll
        for (int rt = 0; rt < 4; ++rt)
            split8(a0[rt], a1[rt], Ah[rt], Am[rt]);
        if (kt < 7) {
            #pragma unroll
            for (int rt = 0; rt < 4; ++rt) {
                const float* s = aPtr + rt * (16 * 256) + (kt + 1) * 32;
                a0[rt] = *(const float4*)s;
                a1[rt] = *(const float4*)(s + 4);
            }
        }
        // pin: all loads above must be issued before the compute cluster
        __builtin_amdgcn_sched_barrier(0);

        const _Float16* Bf = (const _Float16*)(smem + cur * 32768);
        #pragma unroll
        for (int ct = 0; ct < 8; ++ct) {
            int ctg = wc * 8 + ct;
            half8 Bh = *(const half8*)&Bf[(( 0 + ctg) * 64 + lane) * 8];
            half8 Bm = *(const half8*)&Bf[((16 + ctg) * 64 + lane) * 8];
            #pragma unroll
            for (int rt = 0; rt < 4; ++rt) {
                acc[rt][ct] = __builtin_amdgcn_mfma_f32_16x16x32_f16(Ah[rt], Bh, acc[rt][ct], 0, 0, 0);
                acc[rt][ct] = __builtin_amdgcn_mfma_f32_16x16x32_f16(Ah[rt], Bm, acc[rt][ct], 0, 0, 0);
                acc[rt][ct] = __builtin_amdgcn_mfma_f32_16x16x32_f16(Am[rt], Bh, acc[rt][ct], 0, 0, 0);
            }
        }
        __syncthreads();   // next buf + next A landed during compute
    }

    // ---- epilogue: two 128-row passes; tanh -> Pj -> logits = Pj . cc^T
    #pragma unroll
    for (int p = 0; p < 2; ++p) {
        f32x4 acc2[2];
        acc2[0] = (f32x4)(0.0f);
        acc2[1] = (f32x4)(0.0f);
        #pragma unroll
        for (int ec = 0; ec < 4; ++ec) {
            __syncthreads();
            if ((wr >> 1) == p && wc == (ec >> 1)) {
                #pragma unroll
                for (int rt = 0; rt < 4; ++rt) {
                    #pragma unroll
                    for (int c4i = 0; c4i < 4; ++c4i) {
                        int ctm = (ec & 1) * 4 + c4i;
                        f32x4 t = acc[rt][ctm];
                        int el = c4i * 16 + r;
                        int rb = (wr & 1) * 64 + rt * 16 + g * 4;
                        #pragma unroll
                        for (int i = 0; i < 4; ++i)
                            Pj[rb + i][el] = tanh_fast(t[i]);
                    }
                }
            }
            __syncthreads();
            #pragma unroll
            for (int ks = 0; ks < 2; ++ks) {
                half8 Ah2, Am2;
                {
                    const float* src = &Pj[w * 16 + r][ks * 32 + g * 8];
                    float4 p0 = *(const float4*)src;
                    float4 p1 = *(const float4*)(src + 4);
                    split8(p0, p1, Ah2, Am2);
                }
                int et = ec * 2 + ks;
                #pragma unroll
                for (int ct = 0; ct < 2; ++ct) {
                    half8 Bh = Cf[((et * 2 + 0) * 2 + ct) * 64 + lane];
                    half8 Bm = Cf[((et * 2 + 1) * 2 + ct) * 64 + lane];
                    acc2[ct] = __builtin_amdgcn_mfma_f32_16x16x32_f16(Ah2, Bh, acc2[ct], 0, 0, 0);
                    acc2[ct] = __builtin_amdgcn_mfma_f32_16x16x32_f16(Ah2, Bm, acc2[ct], 0, 0, 0);
                    acc2[ct] = __builtin_amdgcn_mfma_f32_16x16x32_f16(Am2, Bh, acc2[ct], 0, 0, 0);
                }
            }
        }
        // store this pass's logits[grow][k] (coalesced; K2 loads this layout)
        #pragma unroll
        for (int ct = 0; ct < 2; ++ct)
            #pragma unroll
            for (int i = 0; i < 4; ++i) {
                size_t grow = rowBase + p * 128 + w * 16 + g * 4 + i;
                logits[grow * 32 + ct * 16 + r] = acc2[ct][i];
            }
    }
}

// K2: per-batch fused mask+softmax -> interests -> aw -> top-k -> user
__global__ __launch_bounds__(256, 3)
void k_attn(const float* __restrict__ hist, const float* __restrict__ cand,
            const int* __restrict__ numi, const int* __restrict__ catc,
            const float* __restrict__ logits, float* __restrict__ out)
{
    __shared__ float wT[100][36];    // weights [l][k]      14400 B
    __shared__ float ints[32][260];  // interests [k][d]    33280 B
    __shared__ float aws[16][36];    //                      2304 B
    __shared__ float maw[16][36];    //                      2304 B  -> 52288 B (3 blk/CU)

    const int tid = threadIdx.x;
    const int b = blockIdx.x;
    const int num = numi[b];

    // load logits [l][k] layout (contiguous 12.8KB per batch)
    for (int idx = tid; idx < 3200; idx += 256) {
        int l = idx >> 5;
        int k = idx & 31;
        wT[l][k] = logits[(size_t)b * 3200 + idx];
    }
    __syncthreads();

    // masked softmax over l, 8 lanes per k-row
    {
        const int k = tid >> 3;
        const int lg = tid & 7;
        const bool valid = k < num;
        float vals[13];
        float m = -INFINITY;
        #pragma unroll
        for (int i = 0; i < 13; ++i) {
            int l = lg + 8 * i;
            if (l < 100) {
                float v = valid ? wT[l][k] : NEGV;
                vals[i] = v;
                m = fmaxf(m, v);
            }
        }
        #pragma unroll
        for (int off = 1; off < 8; off <<= 1)
            m = fmaxf(m, __shfl_xor(m, off, 8));
        float s = 0.0f;
        #pragma unroll
        for (int i = 0; i < 13; ++i) {
            int l = lg + 8 * i;
            if (l < 100) {
                float e = expf(vals[i] - m);
                s += e;
                wT[l][k] = e;
            }
        }
        #pragma unroll
        for (int off = 1; off < 8; off <<= 1)
            s += __shfl_xor(s, off, 8);
        float inv = 1.0f / s;
        #pragma unroll
        for (int i = 0; i < 13; ++i) {
            int l = lg + 8 * i;
            if (l < 100) wT[l][k] *= inv;
        }
    }
    __syncthreads();

    // interests[k][d] = sum_l w[k][l]*hist[b][l][d]
    // thread = (dq = tid&63 -> d=4dq..+3, kh = tid>>6 -> k=8kh..+7)
    {
        const int dq = tid & 63;
        const int kh = tid >> 6;
        float4 a4[8];
        #pragma unroll
        for (int kk = 0; kk < 8; ++kk) { a4[kk].x = a4[kk].y = a4[kk].z = a4[kk].w = 0.0f; }
        const float4* hrow = (const float4*)&hist[(size_t)b * 25600] + dq;
        #pragma unroll 4
        for (int l = 0; l < 100; ++l) {
            float4 hv = hrow[(size_t)l * 64];
            float4 w0 = *(const float4*)&wT[l][8 * kh];
            float4 w1 = *(const float4*)&wT[l][8 * kh + 4];
            float wv[8] = {w0.x, w0.y, w0.z, w0.w, w1.x, w1.y, w1.z, w1.w};
            #pragma unroll
            for (int kk = 0; kk < 8; ++kk) {
                a4[kk].x = fmaf(wv[kk], hv.x, a4[kk].x);
                a4[kk].y = fmaf(wv[kk], hv.y, a4[kk].y);
                a4[kk].z = fmaf(wv[kk], hv.z, a4[kk].z);
                a4[kk].w = fmaf(wv[kk], hv.w, a4[kk].w);
            }
        }
        #pragma unroll
        for (int kk = 0; kk < 8; ++kk)
            *(float4*)&ints[8 * kh + kk][4 * dq] = a4[kk];
    }
    __syncthreads();

    // aw[n][k] = ints[k] . cand[n]; thread = (n = tid&15, kq = tid>>4), k in {kq, kq+16}
    {
        const int n = tid & 15;
        const int kq = tid >> 4;
        const float4* cg = (const float4*)&cand[((size_t)b * 16 + n) * 256];
        const float4* i0 = (const float4*)&ints[kq][0];
        const float4* i1 = (const float4*)&ints[kq + 16][0];
        float s0 = 0.0f, s1 = 0.0f;
        for (int q = 0; q < 64; ++q) {
            float4 cv = cg[q];
            float4 v0 = i0[q];
            float4 v1 = i1[q];
            s0 += v0.x * cv.x + v0.y * cv.y + v0.z * cv.z + v0.w * cv.w;
            s1 += v1.x * cv.x + v1.y * cv.y + v1.z * cv.z + v1.w * cv.w;
        }
        aws[n][kq] = s0;
        aws[n][kq + 16] = s1;
    }
    __syncthreads();

    // stable descending rank + dyn_K mask
    {
        int c = catc[b];
        int dynK = 32 - __clz(2 * c - 1);   // clip(ceil(log2(2c)),1,32) for c in [1,20]
        const int k = tid & 31;
        const int n1 = tid >> 5;
        #pragma unroll
        for (int h = 0; h < 2; ++h) {
            int n = n1 + 8 * h;
            float a = aws[n][k];
            int cnt = 0;
            #pragma unroll
            for (int j = 0; j < 32; ++j) {
                float aj = aws[n][j];
                cnt += (aj > a) || (aj == a && j < k);
            }
            maw[n][k] = (cnt < dynK) ? a : 0.0f;
        }
    }
    __syncthreads();

    // user[n][d] = sum_k maw[n][k] * ints[k][d]
    {
        const int dd = tid & 63;
        const int ng = tid >> 6;
        float4 acc4[4];
        #pragma unroll
        for (int nn = 0; nn < 4; ++nn) { acc4[nn].x = acc4[nn].y = acc4[nn].z = acc4[nn].w = 0.0f; }
        for (int k = 0; k < 32; ++k) {
            float4 iv = *(const float4*)&ints[k][4 * dd];
            #pragma unroll
            for (int nn = 0; nn < 4; ++nn) {
                float m = maw[4 * ng + nn][k];
                acc4[nn].x = fmaf(m, iv.x, acc4[nn].x);
                acc4[nn].y = fmaf(m, iv.y, acc4[nn].y);
                acc4[nn].z = fmaf(m, iv.z, acc4[nn].z);
                acc4[nn].w = fmaf(m, iv.w, acc4[nn].w);
            }
        }
        #pragma unroll
        for (int nn = 0; nn < 4; ++nn) {
            *(float4*)&out[((size_t)b * 16 + 4 * ng + nn) * 256 + 4 * dd] = acc4[nn];
        }
    }
}

extern "C" void kernel_launch(void* const* d_in, const int* in_sizes, int n_in,
                              void* d_out, int out_size, void* d_ws, size_t ws_size,
                              hipStream_t stream) {
    const float* hist = (const float*)d_in[0];
    const float* cand = (const float*)d_in[2];
    const int*   numi = (const int*)d_in[3];
    const int*   catc = (const int*)d_in[4];
    const float* W    = (const float*)d_in[5];
    const float* cc   = (const float*)d_in[6];
    float* out = (float*)d_out;
    float* logits = (float*)d_ws;                 // 26,214,400 B
    const size_t LOG_BYTES = 26214400;
    const size_t WF_BYTES = 262144;               // 8kt x 2spl x 16ct x 64 x 16B
    const size_t CF_BYTES = 32768;                // 8et x 2spl x 2ct x 64 x 16B
    char* fragBase = (ws_size >= LOG_BYTES + WF_BYTES + CF_BYTES)
                     ? ((char*)d_ws + LOG_BYTES)
                     : (char*)d_out;   // d_out fully rewritten by k_attn afterwards
    half8* Wf = (half8*)fragBase;
    half8* Cf = (half8*)(fragBase + WF_BYTES);

    k_prep<<<36, 256, 0, stream>>>(W, cc, Wf, Cf);
    k_proj_logits<<<800, 512, 0, stream>>>(hist, Wf, Cf, logits);
    k_attn<<<2048, 256, 0, stream>>>(hist, cand, numi, catc, logits, out);
}

// Round 13
// 276.707 us; speedup vs baseline: 3.0209x; 3.0209x over previous
//
#include <hip/hip_runtime.h>
#include <math.h>

#define NEGV (-1e9f)

typedef _Float16 half8 __attribute__((ext_vector_type(8)));
typedef float f32x4 __attribute__((ext_vector_type(4)));

// Shapes: BS=2048, L=100, D=256, N=16, K=32
// K1: BM=256 -> 800 blocks x 512 thr (8 waves, wr 0..3 x wc 0..1).
// Wave tile 64 rows x 128 e; 3-product f16-split MFMA (hh, hm, mh).
// r6-winner barrier discipline (issue-early + plain __syncthreads);
// launch_bounds(512,2): 2 waves/SIMD -> VGPR budget 256, no spill (r12's
// (512,4) forced 64 VGPR and spilled acc -> 807MB scratch traffic).
// K2: r11 measured config (~94us), unchanged.

__device__ inline float tanh_fast(float x) {
    float t = __expf(2.0f * x);
    float r = __builtin_amdgcn_rcpf(t + 1.0f);
    return fmaf(-2.0f, r, 1.0f);
}

__device__ inline void split8(const float4 a, const float4 b, half8& h, half8& m) {
    const float* pa = (const float*)&a;
    const float* pb = (const float*)&b;
    #pragma unroll
    for (int q = 0; q < 4; ++q) {
        float x = pa[q];
        _Float16 hi = (_Float16)x;
        h[q] = hi; m[q] = (_Float16)(x - (float)hi);
    }
    #pragma unroll
    for (int q = 0; q < 4; ++q) {
        float x = pb[q];
        _Float16 hi = (_Float16)x;
        h[4+q] = hi; m[4+q] = (_Float16)(x - (float)hi);
    }
}

__device__ inline void gload_lds16(const void* g, void* lds) {
    __builtin_amdgcn_global_load_lds(
        (const __attribute__((address_space(1))) unsigned int*)g,
        (__attribute__((address_space(3))) unsigned int*)lds, 16, 0, 0);
}

// Pre-split W into MFMA frag layout: Wf[((kt*2+spl)*16+ct)*64+lane] (half8)
//   e = ct*16+(lane&15), k-octet g = lane>>4, k = kt*32 + g*8 + j
// Pre-split cc into Cf[((et*2+spl)*2+ct)*64+lane] (half8)
//   k' = ct*16+(lane&15), e = et*32 + (lane>>4)*8 + j
__global__ __launch_bounds__(256)
void k_prep(const float* __restrict__ W, const float* __restrict__ cc,
            half8* __restrict__ Wf, half8* __restrict__ Cf)
{
    int slot = blockIdx.x * 256 + threadIdx.x;   // 9216 slots
    if (slot < 8192) {
        int kt = slot >> 10;
        int ct = (slot >> 6) & 15;
        int lane = slot & 63;
        int e = ct * 16 + (lane & 15);
        int g = lane >> 4;
        const float* src = &W[(size_t)e * 256 + kt * 32 + g * 8];
        float4 a = *(const float4*)src;
        float4 b = *(const float4*)(src + 4);
        half8 h, m;
        split8(a, b, h, m);
        Wf[((kt * 2 + 0) * 16 + ct) * 64 + lane] = h;
        Wf[((kt * 2 + 1) * 16 + ct) * 64 + lane] = m;
    } else if (slot < 9216) {
        int s = slot - 8192;
        int lane = s & 63;
        int ct = (s >> 6) & 1;
        int et = s >> 7;            // 0..7
        int k2 = ct * 16 + (lane & 15);
        int g = lane >> 4;
        const float* src = &cc[(size_t)k2 * 256 + et * 32 + g * 8];
        float4 a = *(const float4*)src;
        float4 b = *(const float4*)(src + 4);
        half8 h, m;
        split8(a, b, h, m);
        Cf[((et * 2 + 0) * 2 + ct) * 64 + lane] = h;
        Cf[((et * 2 + 1) * 2 + ct) * 64 + lane] = m;
    }
}

__global__ __launch_bounds__(512, 2)
void k_proj_logits(const float* __restrict__ hist, const half8* __restrict__ Wf,
                   const half8* __restrict__ Cf, float* __restrict__ logits)
{
    // smem: two 32KB B-frag buffers (double-buffered k-tiles);
    // epilogue aliases smem as Pj float[128][68] (34816 B, per 128-row pass)
    __shared__ __align__(16) char smem[65536];
    float (*Pj)[68] = (float(*)[68])smem;

    const int tid  = threadIdx.x;
    const int lane = tid & 63;
    const int w    = tid >> 6;       // wave 0..7
    const int wr   = w >> 1, wc = w & 1;
    const int g    = lane >> 4;      // k-octet 0..3
    const int r    = lane & 15;      // row/col within 16-tile
    const size_t rowBase = (size_t)blockIdx.x * 256;

    f32x4 acc[4][8];
    #pragma unroll
    for (int i = 0; i < 4; ++i)
        #pragma unroll
        for (int j = 0; j < 8; ++j) acc[i][j] = (f32x4)(0.0f);

    // A source: lane (r,g) reads hist[row][g*8..+7] — directly the A-frag slice
    const float* aPtr = &hist[(rowBase + (size_t)wr * 64 + r) * 256 + g * 8];
    const char*  wsrc = (const char*)Wf + tid * 16;
    const int    ldsW = (tid & 448) * 16;   // wave-uniform part of lds dest

    float4 a0[4], a1[4];
    #pragma unroll
    for (int rt = 0; rt < 4; ++rt) {
        const float* s = aPtr + rt * (16 * 256);
        a0[rt] = *(const float4*)s;
        a1[rt] = *(const float4*)(s + 4);
    }
    // stage B tile 0 into buf 0 (512 thr x 4 x 16B = 32KB)
    #pragma unroll
    for (int i = 0; i < 4; ++i)
        gload_lds16(wsrc + i * 8192, smem + ldsW + i * 8192);
    __syncthreads();   // drains vmcnt: buf0 + A(0) ready

    #pragma unroll 2
    for (int kt = 0; kt < 8; ++kt) {
        const int cur = kt & 1;
        // issue next B-tile stage EARLY (overlap with MFMA below)
        if (kt < 7) {
            const char* s = wsrc + (size_t)(kt + 1) * 32768;
            char* d = smem + (cur ^ 1) * 32768 + ldsW;
            #pragma unroll
            for (int i = 0; i < 4; ++i)
                gload_lds16(s + i * 8192, d + i * 8192);
        }
        // split A for current tile (regs loaded last iteration)
        half8 Ah[4], Am[4];
        #pragma unroll
        for (int rt = 0; rt < 4; ++rt)
            split8(a0[rt], a1[rt], Ah[rt], Am[rt]);
        if (kt < 7) {
            #pragma unroll
            for (int rt = 0; rt < 4; ++rt) {
                const float* s = aPtr + rt * (16 * 256) + (kt + 1) * 32;
                a0[rt] = *(const float4*)s;
                a1[rt] = *(const float4*)(s + 4);
            }
        }
        // pin: all loads above must be issued before the compute cluster
        __builtin_amdgcn_sched_barrier(0);

        const _Float16* Bf = (const _Float16*)(smem + cur * 32768);
        #pragma unroll
        for (int ct = 0; ct < 8; ++ct) {
            int ctg = wc * 8 + ct;
            half8 Bh = *(const half8*)&Bf[(( 0 + ctg) * 64 + lane) * 8];
            half8 Bm = *(const half8*)&Bf[((16 + ctg) * 64 + lane) * 8];
            #pragma unroll
            for (int rt = 0; rt < 4; ++rt) {
                acc[rt][ct] = __builtin_amdgcn_mfma_f32_16x16x32_f16(Ah[rt], Bh, acc[rt][ct], 0, 0, 0);
                acc[rt][ct] = __builtin_amdgcn_mfma_f32_16x16x32_f16(Ah[rt], Bm, acc[rt][ct], 0, 0, 0);
                acc[rt][ct] = __builtin_amdgcn_mfma_f32_16x16x32_f16(Am[rt], Bh, acc[rt][ct], 0, 0, 0);
            }
        }
        __syncthreads();   // next buf + next A landed during compute
    }

    // ---- epilogue: two 128-row passes; tanh -> Pj -> logits = Pj . cc^T
    #pragma unroll
    for (int p = 0; p < 2; ++p) {
        f32x4 acc2[2];
        acc2[0] = (f32x4)(0.0f);
        acc2[1] = (f32x4)(0.0f);
        #pragma unroll
        for (int ec = 0; ec < 4; ++ec) {
            __syncthreads();
            if ((wr >> 1) == p && wc == (ec >> 1)) {
                #pragma unroll
                for (int rt = 0; rt < 4; ++rt) {
                    #pragma unroll
                    for (int c4i = 0; c4i < 4; ++c4i) {
                        int ctm = (ec & 1) * 4 + c4i;
                        f32x4 t = acc[rt][ctm];
                        int el = c4i * 16 + r;
                        int rb = (wr & 1) * 64 + rt * 16 + g * 4;
                        #pragma unroll
                        for (int i = 0; i < 4; ++i)
                            Pj[rb + i][el] = tanh_fast(t[i]);
                    }
                }
            }
            __syncthreads();
            #pragma unroll
            for (int ks = 0; ks < 2; ++ks) {
                half8 Ah2, Am2;
                {
                    const float* src = &Pj[w * 16 + r][ks * 32 + g * 8];
                    float4 p0 = *(const float4*)src;
                    float4 p1 = *(const float4*)(src + 4);
                    split8(p0, p1, Ah2, Am2);
                }
                int et = ec * 2 + ks;
                #pragma unroll
                for (int ct = 0; ct < 2; ++ct) {
                    half8 Bh = Cf[((et * 2 + 0) * 2 + ct) * 64 + lane];
                    half8 Bm = Cf[((et * 2 + 1) * 2 + ct) * 64 + lane];
                    acc2[ct] = __builtin_amdgcn_mfma_f32_16x16x32_f16(Ah2, Bh, acc2[ct], 0, 0, 0);
                    acc2[ct] = __builtin_amdgcn_mfma_f32_16x16x32_f16(Ah2, Bm, acc2[ct], 0, 0, 0);
                    acc2[ct] = __builtin_amdgcn_mfma_f32_16x16x32_f16(Am2, Bh, acc2[ct], 0, 0, 0);
                }
            }
        }
        // store this pass's logits[grow][k] (coalesced; K2 loads this layout)
        #pragma unroll
        for (int ct = 0; ct < 2; ++ct)
            #pragma unroll
            for (int i = 0; i < 4; ++i) {
                size_t grow = rowBase + p * 128 + w * 16 + g * 4 + i;
                logits[grow * 32 + ct * 16 + r] = acc2[ct][i];
            }
    }
}

// K2: per-batch fused mask+softmax -> interests -> aw -> top-k -> user
__global__ __launch_bounds__(256, 3)
void k_attn(const float* __restrict__ hist, const float* __restrict__ cand,
            const int* __restrict__ numi, const int* __restrict__ catc,
            const float* __restrict__ logits, float* __restrict__ out)
{
    __shared__ float wT[100][36];    // weights [l][k]      14400 B
    __shared__ float ints[32][260];  // interests [k][d]    33280 B
    __shared__ float aws[16][36];    //                      2304 B
    __shared__ float maw[16][36];    //                      2304 B  -> 52288 B (3 blk/CU)

    const int tid = threadIdx.x;
    const int b = blockIdx.x;
    const int num = numi[b];

    // load logits [l][k] layout (contiguous 12.8KB per batch)
    for (int idx = tid; idx < 3200; idx += 256) {
        int l = idx >> 5;
        int k = idx & 31;
        wT[l][k] = logits[(size_t)b * 3200 + idx];
    }
    __syncthreads();

    // masked softmax over l, 8 lanes per k-row
    {
        const int k = tid >> 3;
        const int lg = tid & 7;
        const bool valid = k < num;
        float vals[13];
        float m = -INFINITY;
        #pragma unroll
        for (int i = 0; i < 13; ++i) {
            int l = lg + 8 * i;
            if (l < 100) {
                float v = valid ? wT[l][k] : NEGV;
                vals[i] = v;
                m = fmaxf(m, v);
            }
        }
        #pragma unroll
        for (int off = 1; off < 8; off <<= 1)
            m = fmaxf(m, __shfl_xor(m, off, 8));
        float s = 0.0f;
        #pragma unroll
        for (int i = 0; i < 13; ++i) {
            int l = lg + 8 * i;
            if (l < 100) {
                float e = expf(vals[i] - m);
                s += e;
                wT[l][k] = e;
            }
        }
        #pragma unroll
        for (int off = 1; off < 8; off <<= 1)
            s += __shfl_xor(s, off, 8);
        float inv = 1.0f / s;
        #pragma unroll
        for (int i = 0; i < 13; ++i) {
            int l = lg + 8 * i;
            if (l < 100) wT[l][k] *= inv;
        }
    }
    __syncthreads();

    // interests[k][d] = sum_l w[k][l]*hist[b][l][d]
    // thread = (dq = tid&63 -> d=4dq..+3, kh = tid>>6 -> k=8kh..+7)
    {
        const int dq = tid & 63;
        const int kh = tid >> 6;
        float4 a4[8];
        #pragma unroll
        for (int kk = 0; kk < 8; ++kk) { a4[kk].x = a4[kk].y = a4[kk].z = a4[kk].w = 0.0f; }
        const float4* hrow = (const float4*)&hist[(size_t)b * 25600] + dq;
        #pragma unroll 4
        for (int l = 0; l < 100; ++l) {
            float4 hv = hrow[(size_t)l * 64];
            float4 w0 = *(const float4*)&wT[l][8 * kh];
            float4 w1 = *(const float4*)&wT[l][8 * kh + 4];
            float wv[8] = {w0.x, w0.y, w0.z, w0.w, w1.x, w1.y, w1.z, w1.w};
            #pragma unroll
            for (int kk = 0; kk < 8; ++kk) {
                a4[kk].x = fmaf(wv[kk], hv.x, a4[kk].x);
                a4[kk].y = fmaf(wv[kk], hv.y, a4[kk].y);
                a4[kk].z = fmaf(wv[kk], hv.z, a4[kk].z);
                a4[kk].w = fmaf(wv[kk], hv.w, a4[kk].w);
            }
        }
        #pragma unroll
        for (int kk = 0; kk < 8; ++kk)
            *(float4*)&ints[8 * kh + kk][4 * dq] = a4[kk];
    }
    __syncthreads();

    // aw[n][k] = ints[k] . cand[n]; thread = (n = tid&15, kq = tid>>4), k in {kq, kq+16}
    {
        const int n = tid & 15;
        const int kq = tid >> 4;
        const float4* cg = (const float4*)&cand[((size_t)b * 16 + n) * 256];
        const float4* i0 = (const float4*)&ints[kq][0];
        const float4* i1 = (const float4*)&ints[kq + 16][0];
        float s0 = 0.0f, s1 = 0.0f;
        for (int q = 0; q < 64; ++q) {
            float4 cv = cg[q];
            float4 v0 = i0[q];
            float4 v1 = i1[q];
            s0 += v0.x * cv.x + v0.y * cv.y + v0.z * cv.z + v0.w * cv.w;
            s1 += v1.x * cv.x + v1.y * cv.y + v1.z * cv.z + v1.w * cv.w;
        }
        aws[n][kq] = s0;
        aws[n][kq + 16] = s1;
    }
    __syncthreads();

    // stable descending rank + dyn_K mask
    {
        int c = catc[b];
        int dynK = 32 - __clz(2 * c - 1);   // clip(ceil(log2(2c)),1,32) for c in [1,20]
        const int k = tid & 31;
        const int n1 = tid >> 5;
        #pragma unroll
        for (int h = 0; h < 2; ++h) {
            int n = n1 + 8 * h;
            float a = aws[n][k];
            int cnt = 0;
            #pragma unroll
            for (int j = 0; j < 32; ++j) {
                float aj = aws[n][j];
                cnt += (aj > a) || (aj == a && j < k);
            }
            maw[n][k] = (cnt < dynK) ? a : 0.0f;
        }
    }
    __syncthreads();

    // user[n][d] = sum_k maw[n][k] * ints[k][d]
    {
        const int dd = tid & 63;
        const int ng = tid >> 6;
        float4 acc4[4];
        #pragma unroll
        for (int nn = 0; nn < 4; ++nn) { acc4[nn].x = acc4[nn].y = acc4[nn].z = acc4[nn].w = 0.0f; }
        for (int k = 0; k < 32; ++k) {
            float4 iv = *(const float4*)&ints[k][4 * dd];
            #pragma unroll
            for (int nn = 0; nn < 4; ++nn) {
                float m = maw[4 * ng + nn][k];
                acc4[nn].x = fmaf(m, iv.x, acc4[nn].x);
                acc4[nn].y = fmaf(m, iv.y, acc4[nn].y);
                acc4[nn].z = fmaf(m, iv.z, acc4[nn].z);
                acc4[nn].w = fmaf(m, iv.w, acc4[nn].w);
            }
        }
        #pragma unroll
        for (int nn = 0; nn < 4; ++nn) {
            *(float4*)&out[((size_t)b * 16 + 4 * ng + nn) * 256 + 4 * dd] = acc4[nn];
        }
    }
}

extern "C" void kernel_launch(void* const* d_in, const int* in_sizes, int n_in,
                              void* d_out, int out_size, void* d_ws, size_t ws_size,
                              hipStream_t stream) {
    const float* hist = (const float*)d_in[0];
    const float* cand = (const float*)d_in[2];
    const int*   numi = (const int*)d_in[3];
    const int*   catc = (const int*)d_in[4];
    const float* W    = (const float*)d_in[5];
    const float* cc   = (const float*)d_in[6];
    float* out = (float*)d_out;
    float* logits = (float*)d_ws;                 // 26,214,400 B
    const size_t LOG_BYTES = 26214400;
    const size_t WF_BYTES = 262144;               // 8kt x 2spl x 16ct x 64 x 16B
    const size_t CF_BYTES = 32768;                // 8et x 2spl x 2ct x 64 x 16B
    char* fragBase = (ws_size >= LOG_BYTES + WF_BYTES + CF_BYTES)
                     ? ((char*)d_ws + LOG_BYTES)
                     : (char*)d_out;   // d_out fully rewritten by k_attn afterwards
    half8* Wf = (half8*)fragBase;
    half8* Cf = (half8*)(fragBase + WF_BYTES);

    k_prep<<<36, 256, 0, stream>>>(W, cc, Wf, Cf);
    k_proj_logits<<<800, 512, 0, stream>>>(hist, Wf, Cf, logits);
    k_attn<<<2048, 256, 0, stream>>>(hist, cand, numi, catc, logits, out);
}

// Round 14
// 227.807 us; speedup vs baseline: 3.6694x; 1.2147x over previous
//
#include <hip/hip_runtime.h>
#include <math.h>

#define NEGV (-1e9f)

typedef _Float16 half8 __attribute__((ext_vector_type(8)));
typedef float f32x4 __attribute__((ext_vector_type(4)));

// Shapes: BS=2048, L=100, D=256, N=16, K=32
// K1 (r6/r11 measured-best, 136us): M = 204800 rows, BM=128 -> 1600 blocks,
// 256 thr (4 waves, wr x wc = 2x2), wave tile 64 rows x 128 e; 3-product
// f16-split MFMA. A frags in regs; B frags pre-split Wf double-buffered in LDS
// via global_load_lds, issue-early, plain __syncthreads. 2 blk/CU.
// K2: LDS-union (wT aliases ints; interests accumulate in regs) -> 37.9KB
// -> 4 blk/CU (was 3 at 52.3KB). Single-variable change this round.

__device__ inline float tanh_fast(float x) {
    float t = __expf(2.0f * x);
    float r = __builtin_amdgcn_rcpf(t + 1.0f);
    return fmaf(-2.0f, r, 1.0f);
}

__device__ inline void split8(const float4 a, const float4 b, half8& h, half8& m) {
    const float* pa = (const float*)&a;
    const float* pb = (const float*)&b;
    #pragma unroll
    for (int q = 0; q < 4; ++q) {
        float x = pa[q];
        _Float16 hi = (_Float16)x;
        h[q] = hi; m[q] = (_Float16)(x - (float)hi);
    }
    #pragma unroll
    for (int q = 0; q < 4; ++q) {
        float x = pb[q];
        _Float16 hi = (_Float16)x;
        h[4+q] = hi; m[4+q] = (_Float16)(x - (float)hi);
    }
}

__device__ inline void gload_lds16(const void* g, void* lds) {
    __builtin_amdgcn_global_load_lds(
        (const __attribute__((address_space(1))) unsigned int*)g,
        (__attribute__((address_space(3))) unsigned int*)lds, 16, 0, 0);
}

// Pre-split W into MFMA frag layout: Wf[((kt*2+spl)*16+ct)*64+lane] (half8)
//   e = ct*16+(lane&15), k-octet g = lane>>4, k = kt*32 + g*8 + j
// Pre-split cc into Cf[((et*2+spl)*2+ct)*64+lane] (half8)
//   k' = ct*16+(lane&15), e = et*32 + (lane>>4)*8 + j
__global__ __launch_bounds__(256)
void k_prep(const float* __restrict__ W, const float* __restrict__ cc,
            half8* __restrict__ Wf, half8* __restrict__ Cf)
{
    int slot = blockIdx.x * 256 + threadIdx.x;   // 9216 slots
    if (slot < 8192) {
        int kt = slot >> 10;
        int ct = (slot >> 6) & 15;
        int lane = slot & 63;
        int e = ct * 16 + (lane & 15);
        int g = lane >> 4;
        const float* src = &W[(size_t)e * 256 + kt * 32 + g * 8];
        float4 a = *(const float4*)src;
        float4 b = *(const float4*)(src + 4);
        half8 h, m;
        split8(a, b, h, m);
        Wf[((kt * 2 + 0) * 16 + ct) * 64 + lane] = h;
        Wf[((kt * 2 + 1) * 16 + ct) * 64 + lane] = m;
    } else if (slot < 9216) {
        int s = slot - 8192;
        int lane = s & 63;
        int ct = (s >> 6) & 1;
        int et = s >> 7;            // 0..7
        int k2 = ct * 16 + (lane & 15);
        int g = lane >> 4;
        const float* src = &cc[(size_t)k2 * 256 + et * 32 + g * 8];
        float4 a = *(const float4*)src;
        float4 b = *(const float4*)(src + 4);
        half8 h, m;
        split8(a, b, h, m);
        Cf[((et * 2 + 0) * 2 + ct) * 64 + lane] = h;
        Cf[((et * 2 + 1) * 2 + ct) * 64 + lane] = m;
    }
}

__global__ __launch_bounds__(256, 2)
void k_proj_logits(const float* __restrict__ hist, const half8* __restrict__ Wf,
                   const half8* __restrict__ Cf, float* __restrict__ logits)
{
    // smem: two 32KB B-frag buffers (double-buffered k-tiles);
    // epilogue aliases smem as Pj float[128][68] (34816 B)
    __shared__ __align__(16) char smem[65536];
    float (*Pj)[68] = (float(*)[68])smem;

    const int tid  = threadIdx.x;
    const int lane = tid & 63;
    const int w    = tid >> 6;       // wave 0..3
    const int wr   = w >> 1, wc = w & 1;
    const int g    = lane >> 4;      // k-octet 0..3
    const int r    = lane & 15;      // row/col within 16-tile
    const size_t rowBase = (size_t)blockIdx.x * 128;

    f32x4 acc[4][8];
    #pragma unroll
    for (int i = 0; i < 4; ++i)
        #pragma unroll
        for (int j = 0; j < 8; ++j) acc[i][j] = (f32x4)(0.0f);

    // A source: lane (r,g) reads hist[row][g*8..+7] — directly the A-frag slice
    const float* aPtr = &hist[(rowBase + (size_t)wr * 64 + r) * 256 + g * 8];
    const char*  wsrc = (const char*)Wf + tid * 16;
    const int    ldsW = (tid & 192) * 16;   // wave-uniform part of lds dest

    float4 a0[4], a1[4];
    #pragma unroll
    for (int rt = 0; rt < 4; ++rt) {
        const float* s = aPtr + rt * (16 * 256);
        a0[rt] = *(const float4*)s;
        a1[rt] = *(const float4*)(s + 4);
    }
    // stage B tile 0 into buf 0
    #pragma unroll
    for (int i = 0; i < 8; ++i)
        gload_lds16(wsrc + i * 4096, smem + ldsW + i * 4096);
    __syncthreads();   // drains vmcnt: buf0 + A(0) ready

    #pragma unroll 2
    for (int kt = 0; kt < 8; ++kt) {
        const int cur = kt & 1;
        // issue next B-tile stage EARLY (overlap with MFMA below)
        if (kt < 7) {
            const char* s = wsrc + (size_t)(kt + 1) * 32768;
            char* d = smem + (cur ^ 1) * 32768 + ldsW;
            #pragma unroll
            for (int i = 0; i < 8; ++i)
                gload_lds16(s + i * 4096, d + i * 4096);
        }
        // split A for current tile (regs loaded last iteration)
        half8 Ah[4], Am[4];
        #pragma unroll
        for (int rt = 0; rt < 4; ++rt)
            split8(a0[rt], a1[rt], Ah[rt], Am[rt]);
        if (kt < 7) {
            #pragma unroll
            for (int rt = 0; rt < 4; ++rt) {
                const float* s = aPtr + rt * (16 * 256) + (kt + 1) * 32;
                a0[rt] = *(const float4*)s;
                a1[rt] = *(const float4*)(s + 4);
            }
        }
        // pin: all loads above must be issued before the compute cluster
        __builtin_amdgcn_sched_barrier(0);

        const _Float16* Bf = (const _Float16*)(smem + cur * 32768);
        #pragma unroll
        for (int ct = 0; ct < 8; ++ct) {
            int ctg = wc * 8 + ct;
            half8 Bh = *(const half8*)&Bf[(( 0 + ctg) * 64 + lane) * 8];
            half8 Bm = *(const half8*)&Bf[((16 + ctg) * 64 + lane) * 8];
            #pragma unroll
            for (int rt = 0; rt < 4; ++rt) {
                acc[rt][ct] = __builtin_amdgcn_mfma_f32_16x16x32_f16(Ah[rt], Bh, acc[rt][ct], 0, 0, 0);
                acc[rt][ct] = __builtin_amdgcn_mfma_f32_16x16x32_f16(Ah[rt], Bm, acc[rt][ct], 0, 0, 0);
                acc[rt][ct] = __builtin_amdgcn_mfma_f32_16x16x32_f16(Am[rt], Bh, acc[rt][ct], 0, 0, 0);
            }
        }
        __syncthreads();   // next buf + next A landed during compute
    }

    // ---- epilogue: tanh -> Pj (fp32, 4 e-chunks of 64) -> logits = Pj . cc^T
    f32x4 acc2[2][2];
    #pragma unroll
    for (int i = 0; i < 2; ++i)
        #pragma unroll
        for (int j = 0; j < 2; ++j) acc2[i][j] = (f32x4)(0.0f);

    #pragma unroll
    for (int ec = 0; ec < 4; ++ec) {
        __syncthreads();
        if (wc == (ec >> 1)) {
            #pragma unroll
            for (int rt = 0; rt < 4; ++rt) {
                #pragma unroll
                for (int c4i = 0; c4i < 4; ++c4i) {
                    int ctm = (ec & 1) * 4 + c4i;
                    f32x4 t = acc[rt][ctm];
                    int el = c4i * 16 + r;
                    int rb = 64 * wr + rt * 16 + g * 4;
                    #pragma unroll
                    for (int i = 0; i < 4; ++i)
                        Pj[rb + i][el] = tanh_fast(t[i]);
                }
            }
        }
        __syncthreads();
        #pragma unroll
        for (int ks = 0; ks < 2; ++ks) {
            half8 Ah2[2], Am2[2];
            #pragma unroll
            for (int rt2 = 0; rt2 < 2; ++rt2) {
                const float* src = &Pj[32 * w + rt2 * 16 + r][ks * 32 + g * 8];
                float4 p0 = *(const float4*)src;
                float4 p1 = *(const float4*)(src + 4);
                split8(p0, p1, Ah2[rt2], Am2[rt2]);
            }
            int et = ec * 2 + ks;
            #pragma unroll
            for (int ct = 0; ct < 2; ++ct) {
                half8 Bh = Cf[((et * 2 + 0) * 2 + ct) * 64 + lane];
                half8 Bm = Cf[((et * 2 + 1) * 2 + ct) * 64 + lane];
                #pragma unroll
                for (int rt2 = 0; rt2 < 2; ++rt2) {
                    acc2[rt2][ct] = __builtin_amdgcn_mfma_f32_16x16x32_f16(Ah2[rt2], Bh, acc2[rt2][ct], 0, 0, 0);
                    acc2[rt2][ct] = __builtin_amdgcn_mfma_f32_16x16x32_f16(Ah2[rt2], Bm, acc2[rt2][ct], 0, 0, 0);
                    acc2[rt2][ct] = __builtin_amdgcn_mfma_f32_16x16x32_f16(Am2[rt2], Bh, acc2[rt2][ct], 0, 0, 0);
                }
            }
        }
    }
    // store logits[grow][k] (coalesced; K2 loads this layout)
    #pragma unroll
    for (int rt2 = 0; rt2 < 2; ++rt2)
        #pragma unroll
        for (int ct = 0; ct < 2; ++ct)
            #pragma unroll
            for (int i = 0; i < 4; ++i) {
                size_t grow = rowBase + 32 * w + rt2 * 16 + g * 4 + i;
                logits[grow * 32 + ct * 16 + r] = acc2[rt2][ct][i];
            }
}

// K2: per-batch fused mask+softmax -> interests -> aw -> top-k -> user
// LDS union: wT[100][36] (14.4KB) aliases the front of ints[32][260] (33.3KB).
// interests accumulate in registers while reading wT; after a barrier the
// ints write overwrites the wT region. Total LDS 37888 B -> 4 blk/CU.
__global__ __launch_bounds__(256, 4)
void k_attn(const float* __restrict__ hist, const float* __restrict__ cand,
            const int* __restrict__ numi, const int* __restrict__ catc,
            const float* __restrict__ logits, float* __restrict__ out)
{
    __shared__ __align__(16) char smem[37888];
    float (*ints)[260] = (float(*)[260])smem;            // 33280 B (phase B)
    float (*wT)[36]    = (float(*)[36])smem;             // 14400 B (phase A, aliased)
    float (*aws)[36]   = (float(*)[36])(smem + 33280);   //  2304 B
    float (*maw)[36]   = (float(*)[36])(smem + 35584);   //  2304 B

    const int tid = threadIdx.x;
    const int b = blockIdx.x;
    const int num = numi[b];

    // load logits [l][k] layout (contiguous 12.8KB per batch)
    for (int idx = tid; idx < 3200; idx += 256) {
        int l = idx >> 5;
        int k = idx & 31;
        wT[l][k] = logits[(size_t)b * 3200 + idx];
    }
    __syncthreads();

    // masked softmax over l, 8 lanes per k-row
    {
        const int k = tid >> 3;
        const int lg = tid & 7;
        const bool valid = k < num;
        float vals[13];
        float m = -INFINITY;
        #pragma unroll
        for (int i = 0; i < 13; ++i) {
            int l = lg + 8 * i;
            if (l < 100) {
                float v = valid ? wT[l][k] : NEGV;
                vals[i] = v;
                m = fmaxf(m, v);
            }
        }
        #pragma unroll
        for (int off = 1; off < 8; off <<= 1)
            m = fmaxf(m, __shfl_xor(m, off, 8));
        float s = 0.0f;
        #pragma unroll
        for (int i = 0; i < 13; ++i) {
            int l = lg + 8 * i;
            if (l < 100) {
                float e = expf(vals[i] - m);
                s += e;
                wT[l][k] = e;
            }
        }
        #pragma unroll
        for (int off = 1; off < 8; off <<= 1)
            s += __shfl_xor(s, off, 8);
        float inv = 1.0f / s;
        #pragma unroll
        for (int i = 0; i < 13; ++i) {
            int l = lg + 8 * i;
            if (l < 100) wT[l][k] *= inv;
        }
    }
    __syncthreads();

    // interests[k][d] = sum_l w[k][l]*hist[b][l][d] — accumulate in REGISTERS
    // thread = (dq = tid&63 -> d=4dq..+3, kh = tid>>6 -> k=8kh..+7)
    {
        const int dq = tid & 63;
        const int kh = tid >> 6;
        float4 a4[8];
        #pragma unroll
        for (int kk = 0; kk < 8; ++kk) { a4[kk].x = a4[kk].y = a4[kk].z = a4[kk].w = 0.0f; }
        const float4* hrow = (const float4*)&hist[(size_t)b * 25600] + dq;
        #pragma unroll 4
        for (int l = 0; l < 100; ++l) {
            float4 hv = hrow[(size_t)l * 64];
            float4 w0 = *(const float4*)&wT[l][8 * kh];
            float4 w1 = *(const float4*)&wT[l][8 * kh + 4];
            float wv[8] = {w0.x, w0.y, w0.z, w0.w, w1.x, w1.y, w1.z, w1.w};
            #pragma unroll
            for (int kk = 0; kk < 8; ++kk) {
                a4[kk].x = fmaf(wv[kk], hv.x, a4[kk].x);
                a4[kk].y = fmaf(wv[kk], hv.y, a4[kk].y);
                a4[kk].z = fmaf(wv[kk], hv.z, a4[kk].z);
                a4[kk].w = fmaf(wv[kk], hv.w, a4[kk].w);
            }
        }
        __syncthreads();   // all wT reads done -> safe to overwrite with ints
        #pragma unroll
        for (int kk = 0; kk < 8; ++kk)
            *(float4*)&ints[8 * kh + kk][4 * dq] = a4[kk];
    }
    __syncthreads();

    // aw[n][k] = ints[k] . cand[n]; thread = (n = tid&15, kq = tid>>4), k in {kq, kq+16}
    {
        const int n = tid & 15;
        const int kq = tid >> 4;
        const float4* cg = (const float4*)&cand[((size_t)b * 16 + n) * 256];
        const float4* i0 = (const float4*)&ints[kq][0];
        const float4* i1 = (const float4*)&ints[kq + 16][0];
        float s0 = 0.0f, s1 = 0.0f;
        for (int q = 0; q < 64; ++q) {
            float4 cv = cg[q];
            float4 v0 = i0[q];
            float4 v1 = i1[q];
            s0 += v0.x * cv.x + v0.y * cv.y + v0.z * cv.z + v0.w * cv.w;
            s1 += v1.x * cv.x + v1.y * cv.y + v1.z * cv.z + v1.w * cv.w;
        }
        aws[n][kq] = s0;
        aws[n][kq + 16] = s1;
    }
    __syncthreads();

    // stable descending rank + dyn_K mask
    {
        int c = catc[b];
        int dynK = 32 - __clz(2 * c - 1);   // clip(ceil(log2(2c)),1,32) for c in [1,20]
        const int k = tid & 31;
        const int n1 = tid >> 5;
        #pragma unroll
        for (int h = 0; h < 2; ++h) {
            int n = n1 + 8 * h;
            float a = aws[n][k];
            int cnt = 0;
            #pragma unroll
            for (int j = 0; j < 32; ++j) {
                float aj = aws[n][j];
                cnt += (aj > a) || (aj == a && j < k);
            }
            maw[n][k] = (cnt < dynK) ? a : 0.0f;
        }
    }
    __syncthreads();

    // user[n][d] = sum_k maw[n][k] * ints[k][d]
    {
        const int dd = tid & 63;
        const int ng = tid >> 6;
        float4 acc4[4];
        #pragma unroll
        for (int nn = 0; nn < 4; ++nn) { acc4[nn].x = acc4[nn].y = acc4[nn].z = acc4[nn].w = 0.0f; }
        for (int k = 0; k < 32; ++k) {
            float4 iv = *(const float4*)&ints[k][4 * dd];
            #pragma unroll
            for (int nn = 0; nn < 4; ++nn) {
                float m = maw[4 * ng + nn][k];
                acc4[nn].x = fmaf(m, iv.x, acc4[nn].x);
                acc4[nn].y = fmaf(m, iv.y, acc4[nn].y);
                acc4[nn].z = fmaf(m, iv.z, acc4[nn].z);
                acc4[nn].w = fmaf(m, iv.w, acc4[nn].w);
            }
        }
        #pragma unroll
        for (int nn = 0; nn < 4; ++nn) {
            *(float4*)&out[((size_t)b * 16 + 4 * ng + nn) * 256 + 4 * dd] = acc4[nn];
        }
    }
}

extern "C" void kernel_launch(void* const* d_in, const int* in_sizes, int n_in,
                              void* d_out, int out_size, void* d_ws, size_t ws_size,
                              hipStream_t stream) {
    const float* hist = (const float*)d_in[0];
    const float* cand = (const float*)d_in[2];
    const int*   numi = (const int*)d_in[3];
    const int*   catc = (const int*)d_in[4];
    const float* W    = (const float*)d_in[5];
    const float* cc   = (const float*)d_in[6];
    float* out = (float*)d_out;
    float* logits = (float*)d_ws;                 // 26,214,400 B
    const size_t LOG_BYTES = 26214400;
    const size_t WF_BYTES = 262144;               // 8kt x 2spl x 16ct x 64 x 16B
    const size_t CF_BYTES = 32768;                // 8et x 2spl x 2ct x 64 x 16B
    char* fragBase = (ws_size >= LOG_BYTES + WF_BYTES + CF_BYTES)
                     ? ((char*)d_ws + LOG_BYTES)
                     : (char*)d_out;   // d_out fully rewritten by k_attn afterwards
    half8* Wf = (half8*)fragBase;
    half8* Cf = (half8*)(fragBase + WF_BYTES);

    k_prep<<<36, 256, 0, stream>>>(W, cc, Wf, Cf);
    k_proj_logits<<<1600, 256, 0, stream>>>(hist, Wf, Cf, logits);
    k_attn<<<2048, 256, 0, stream>>>(hist, cand, numi, catc, logits, out);
}

// Round 16
// 227.673 us; speedup vs baseline: 3.6716x; 1.0006x over previous
//
#include <hip/hip_runtime.h>
#include <math.h>

#define NEGV (-1e9f)

typedef _Float16 half8 __attribute__((ext_vector_type(8)));
typedef __fp16 fp16x2 __attribute__((ext_vector_type(2)));
typedef float f32x4 __attribute__((ext_vector_type(4)));

// Shapes: BS=2048, L=100, D=256, N=16, K=32
// K1 (r6/r11 measured-best structure, 136us): M = 204800 rows, BM=128 ->
// 1600 blocks, 256 thr (4 waves, wr x wc = 2x2), wave tile 64 rows x 128 e;
// 3-product f16-split MFMA. A frags in regs; B frags pre-split Wf
// double-buffered in LDS via global_load_lds, issue-early, plain __syncthreads.
// THIS ROUND (single variable): split8 uses v_cvt_pkrtz_f16_f32 packed
// converts -> fewer VALU ops per split (6 ops/2 elems vs 8).
// K2: r14 measured config (LDS-union, 4 blk/CU), unchanged.

__device__ inline float tanh_fast(float x) {
    float t = __expf(2.0f * x);
    float r = __builtin_amdgcn_rcpf(t + 1.0f);
    return fmaf(-2.0f, r, 1.0f);
}

// f32 -> f16 high + f16 residual split using packed RTZ converts.
// hi = rtz_f16(x); res = x - (float)hi is exact (Sterbenz); m = rtz_f16(res).
// Dropped-term bound ~2^-21 relative — well under threshold.
__device__ inline void split8(const float4 a, const float4 b, half8& h, half8& m) {
    const float x[8] = {a.x, a.y, a.z, a.w, b.x, b.y, b.z, b.w};
    #pragma unroll
    for (int q = 0; q < 4; ++q) {
        fp16x2 hp = __builtin_amdgcn_cvt_pkrtz(x[2 * q], x[2 * q + 1]);
        float r0 = x[2 * q]     - (float)hp[0];
        float r1 = x[2 * q + 1] - (float)hp[1];
        fp16x2 mp = __builtin_amdgcn_cvt_pkrtz(r0, r1);
        h[2 * q] = (_Float16)hp[0]; h[2 * q + 1] = (_Float16)hp[1];
        m[2 * q] = (_Float16)mp[0]; m[2 * q + 1] = (_Float16)mp[1];
    }
}

__device__ inline void gload_lds16(const void* g, void* lds) {
    __builtin_amdgcn_global_load_lds(
        (const __attribute__((address_space(1))) unsigned int*)g,
        (__attribute__((address_space(3))) unsigned int*)lds, 16, 0, 0);
}

// Pre-split W into MFMA frag layout: Wf[((kt*2+spl)*16+ct)*64+lane] (half8)
//   e = ct*16+(lane&15), k-octet g = lane>>4, k = kt*32 + g*8 + j
// Pre-split cc into Cf[((et*2+spl)*2+ct)*64+lane] (half8)
//   k' = ct*16+(lane&15), e = et*32 + (lane>>4)*8 + j
__global__ __launch_bounds__(256)
void k_prep(const float* __restrict__ W, const float* __restrict__ cc,
            half8* __restrict__ Wf, half8* __restrict__ Cf)
{
    int slot = blockIdx.x * 256 + threadIdx.x;   // 9216 slots
    if (slot < 8192) {
        int kt = slot >> 10;
        int ct = (slot >> 6) & 15;
        int lane = slot & 63;
        int e = ct * 16 + (lane & 15);
        int g = lane >> 4;
        const float* src = &W[(size_t)e * 256 + kt * 32 + g * 8];
        float4 a = *(const float4*)src;
        float4 b = *(const float4*)(src + 4);
        half8 h, m;
        split8(a, b, h, m);
        Wf[((kt * 2 + 0) * 16 + ct) * 64 + lane] = h;
        Wf[((kt * 2 + 1) * 16 + ct) * 64 + lane] = m;
    } else if (slot < 9216) {
        int s = slot - 8192;
        int lane = s & 63;
        int ct = (s >> 6) & 1;
        int et = s >> 7;            // 0..7
        int k2 = ct * 16 + (lane & 15);
        int g = lane >> 4;
        const float* src = &cc[(size_t)k2 * 256 + et * 32 + g * 8];
        float4 a = *(const float4*)src;
        float4 b = *(const float4*)(src + 4);
        half8 h, m;
        split8(a, b, h, m);
        Cf[((et * 2 + 0) * 2 + ct) * 64 + lane] = h;
        Cf[((et * 2 + 1) * 2 + ct) * 64 + lane] = m;
    }
}

__global__ __launch_bounds__(256, 2)
void k_proj_logits(const float* __restrict__ hist, const half8* __restrict__ Wf,
                   const half8* __restrict__ Cf, float* __restrict__ logits)
{
    // smem: two 32KB B-frag buffers (double-buffered k-tiles);
    // epilogue aliases smem as Pj float[128][68] (34816 B)
    __shared__ __align__(16) char smem[65536];
    float (*Pj)[68] = (float(*)[68])smem;

    const int tid  = threadIdx.x;
    const int lane = tid & 63;
    const int w    = tid >> 6;       // wave 0..3
    const int wr   = w >> 1, wc = w & 1;
    const int g    = lane >> 4;      // k-octet 0..3
    const int r    = lane & 15;      // row/col within 16-tile
    const size_t rowBase = (size_t)blockIdx.x * 128;

    f32x4 acc[4][8];
    #pragma unroll
    for (int i = 0; i < 4; ++i)
        #pragma unroll
        for (int j = 0; j < 8; ++j) acc[i][j] = (f32x4)(0.0f);

    // A source: lane (r,g) reads hist[row][g*8..+7] — directly the A-frag slice
    const float* aPtr = &hist[(rowBase + (size_t)wr * 64 + r) * 256 + g * 8];
    const char*  wsrc = (const char*)Wf + tid * 16;
    const int    ldsW = (tid & 192) * 16;   // wave-uniform part of lds dest

    float4 a0[4], a1[4];
    #pragma unroll
    for (int rt = 0; rt < 4; ++rt) {
        const float* s = aPtr + rt * (16 * 256);
        a0[rt] = *(const float4*)s;
        a1[rt] = *(const float4*)(s + 4);
    }
    // stage B tile 0 into buf 0
    #pragma unroll
    for (int i = 0; i < 8; ++i)
        gload_lds16(wsrc + i * 4096, smem + ldsW + i * 4096);
    __syncthreads();   // drains vmcnt: buf0 + A(0) ready

    #pragma unroll 2
    for (int kt = 0; kt < 8; ++kt) {
        const int cur = kt & 1;
        // issue next B-tile stage EARLY (overlap with MFMA below)
        if (kt < 7) {
            const char* s = wsrc + (size_t)(kt + 1) * 32768;
            char* d = smem + (cur ^ 1) * 32768 + ldsW;
            #pragma unroll
            for (int i = 0; i < 8; ++i)
                gload_lds16(s + i * 4096, d + i * 4096);
        }
        // split A for current tile (regs loaded last iteration)
        half8 Ah[4], Am[4];
        #pragma unroll
        for (int rt = 0; rt < 4; ++rt)
            split8(a0[rt], a1[rt], Ah[rt], Am[rt]);
        if (kt < 7) {
            #pragma unroll
            for (int rt = 0; rt < 4; ++rt) {
                const float* s = aPtr + rt * (16 * 256) + (kt + 1) * 32;
                a0[rt] = *(const float4*)s;
                a1[rt] = *(const float4*)(s + 4);
            }
        }
        // pin: all loads above must be issued before the compute cluster
        __builtin_amdgcn_sched_barrier(0);

        const _Float16* Bf = (const _Float16*)(smem + cur * 32768);
        #pragma unroll
        for (int ct = 0; ct < 8; ++ct) {
            int ctg = wc * 8 + ct;
            half8 Bh = *(const half8*)&Bf[(( 0 + ctg) * 64 + lane) * 8];
            half8 Bm = *(const half8*)&Bf[((16 + ctg) * 64 + lane) * 8];
            #pragma unroll
            for (int rt = 0; rt < 4; ++rt) {
                acc[rt][ct] = __builtin_amdgcn_mfma_f32_16x16x32_f16(Ah[rt], Bh, acc[rt][ct], 0, 0, 0);
                acc[rt][ct] = __builtin_amdgcn_mfma_f32_16x16x32_f16(Ah[rt], Bm, acc[rt][ct], 0, 0, 0);
                acc[rt][ct] = __builtin_amdgcn_mfma_f32_16x16x32_f16(Am[rt], Bh, acc[rt][ct], 0, 0, 0);
            }
        }
        __syncthreads();   // next buf + next A landed during compute
    }

    // ---- epilogue: tanh -> Pj (fp32, 4 e-chunks of 64) -> logits = Pj . cc^T
    f32x4 acc2[2][2];
    #pragma unroll
    for (int i = 0; i < 2; ++i)
        #pragma unroll
        for (int j = 0; j < 2; ++j) acc2[i][j] = (f32x4)(0.0f);

    #pragma unroll
    for (int ec = 0; ec < 4; ++ec) {
        __syncthreads();
        if (wc == (ec >> 1)) {
            #pragma unroll
            for (int rt = 0; rt < 4; ++rt) {
                #pragma unroll
                for (int c4i = 0; c4i < 4; ++c4i) {
                    int ctm = (ec & 1) * 4 + c4i;
                    f32x4 t = acc[rt][ctm];
                    int el = c4i * 16 + r;
                    int rb = 64 * wr + rt * 16 + g * 4;
                    #pragma unroll
                    for (int i = 0; i < 4; ++i)
                        Pj[rb + i][el] = tanh_fast(t[i]);
                }
            }
        }
        __syncthreads();
        #pragma unroll
        for (int ks = 0; ks < 2; ++ks) {
            half8 Ah2[2], Am2[2];
            #pragma unroll
            for (int rt2 = 0; rt2 < 2; ++rt2) {
                const float* src = &Pj[32 * w + rt2 * 16 + r][ks * 32 + g * 8];
                float4 p0 = *(const float4*)src;
                float4 p1 = *(const float4*)(src + 4);
                split8(p0, p1, Ah2[rt2], Am2[rt2]);
            }
            int et = ec * 2 + ks;
            #pragma unroll
            for (int ct = 0; ct < 2; ++ct) {
                half8 Bh = Cf[((et * 2 + 0) * 2 + ct) * 64 + lane];
                half8 Bm = Cf[((et * 2 + 1) * 2 + ct) * 64 + lane];
                #pragma unroll
                for (int rt2 = 0; rt2 < 2; ++rt2) {
                    acc2[rt2][ct] = __builtin_amdgcn_mfma_f32_16x16x32_f16(Ah2[rt2], Bh, acc2[rt2][ct], 0, 0, 0);
                    acc2[rt2][ct] = __builtin_amdgcn_mfma_f32_16x16x32_f16(Ah2[rt2], Bm, acc2[rt2][ct], 0, 0, 0);
                    acc2[rt2][ct] = __builtin_amdgcn_mfma_f32_16x16x32_f16(Am2[rt2], Bh, acc2[rt2][ct], 0, 0, 0);
                }
            }
        }
    }
    // store logits[grow][k] (coalesced; K2 loads this layout)
    #pragma unroll
    for (int rt2 = 0; rt2 < 2; ++rt2)
        #pragma unroll
        for (int ct = 0; ct < 2; ++ct)
            #pragma unroll
            for (int i = 0; i < 4; ++i) {
                size_t grow = rowBase + 32 * w + rt2 * 16 + g * 4 + i;
                logits[grow * 32 + ct * 16 + r] = acc2[rt2][ct][i];
            }
}

// K2: per-batch fused mask+softmax -> interests -> aw -> top-k -> user
// LDS union: wT[100][36] (14.4KB) aliases the front of ints[32][260] (33.3KB).
// interests accumulate in registers while reading wT; after a barrier the
// ints write overwrites the wT region. Total LDS 37888 B -> 4 blk/CU.
__global__ __launch_bounds__(256, 4)
void k_attn(const float* __restrict__ hist, const float* __restrict__ cand,
            const int* __restrict__ numi, const int* __restrict__ catc,
            const float* __restrict__ logits, float* __restrict__ out)
{
    __shared__ __align__(16) char smem[37888];
    float (*ints)[260] = (float(*)[260])smem;            // 33280 B (phase B)
    float (*wT)[36]    = (float(*)[36])smem;             // 14400 B (phase A, aliased)
    float (*aws)[36]   = (float(*)[36])(smem + 33280);   //  2304 B
    float (*maw)[36]   = (float(*)[36])(smem + 35584);   //  2304 B

    const int tid = threadIdx.x;
    const int b = blockIdx.x;
    const int num = numi[b];

    // load logits [l][k] layout (contiguous 12.8KB per batch)
    for (int idx = tid; idx < 3200; idx += 256) {
        int l = idx >> 5;
        int k = idx & 31;
        wT[l][k] = logits[(size_t)b * 3200 + idx];
    }
    __syncthreads();

    // masked softmax over l, 8 lanes per k-row
    {
        const int k = tid >> 3;
        const int lg = tid & 7;
        const bool valid = k < num;
        float vals[13];
        float m = -INFINITY;
        #pragma unroll
        for (int i = 0; i < 13; ++i) {
            int l = lg + 8 * i;
            if (l < 100) {
                float v = valid ? wT[l][k] : NEGV;
                vals[i] = v;
                m = fmaxf(m, v);
            }
        }
        #pragma unroll
        for (int off = 1; off < 8; off <<= 1)
            m = fmaxf(m, __shfl_xor(m, off, 8));
        float s = 0.0f;
        #pragma unroll
        for (int i = 0; i < 13; ++i) {
            int l = lg + 8 * i;
            if (l < 100) {
                float e = expf(vals[i] - m);
                s += e;
                wT[l][k] = e;
            }
        }
        #pragma unroll
        for (int off = 1; off < 8; off <<= 1)
            s += __shfl_xor(s, off, 8);
        float inv = 1.0f / s;
        #pragma unroll
        for (int i = 0; i < 13; ++i) {
            int l = lg + 8 * i;
            if (l < 100) wT[l][k] *= inv;
        }
    }
    __syncthreads();

    // interests[k][d] = sum_l w[k][l]*hist[b][l][d] — accumulate in REGISTERS
    // thread = (dq = tid&63 -> d=4dq..+3, kh = tid>>6 -> k=8kh..+7)
    {
        const int dq = tid & 63;
        const int kh = tid >> 6;
        float4 a4[8];
        #pragma unroll
        for (int kk = 0; kk < 8; ++kk) { a4[kk].x = a4[kk].y = a4[kk].z = a4[kk].w = 0.0f; }
        const float4* hrow = (const float4*)&hist[(size_t)b * 25600] + dq;
        #pragma unroll 4
        for (int l = 0; l < 100; ++l) {
            float4 hv = hrow[(size_t)l * 64];
            float4 w0 = *(const float4*)&wT[l][8 * kh];
            float4 w1 = *(const float4*)&wT[l][8 * kh + 4];
            float wv[8] = {w0.x, w0.y, w0.z, w0.w, w1.x, w1.y, w1.z, w1.w};
            #pragma unroll
            for (int kk = 0; kk < 8; ++kk) {
                a4[kk].x = fmaf(wv[kk], hv.x, a4[kk].x);
                a4[kk].y = fmaf(wv[kk], hv.y, a4[kk].y);
                a4[kk].z = fmaf(wv[kk], hv.z, a4[kk].z);
                a4[kk].w = fmaf(wv[kk], hv.w, a4[kk].w);
            }
        }
        __syncthreads();   // all wT reads done -> safe to overwrite with ints
        #pragma unroll
        for (int kk = 0; kk < 8; ++kk)
            *(float4*)&ints[8 * kh + kk][4 * dq] = a4[kk];
    }
    __syncthreads();

    // aw[n][k] = ints[k] . cand[n]; thread = (n = tid&15, kq = tid>>4), k in {kq, kq+16}
    {
        const int n = tid & 15;
        const int kq = tid >> 4;
        const float4* cg = (const float4*)&cand[((size_t)b * 16 + n) * 256];
        const float4* i0 = (const float4*)&ints[kq][0];
        const float4* i1 = (const float4*)&ints[kq + 16][0];
        float s0 = 0.0f, s1 = 0.0f;
        for (int q = 0; q < 64; ++q) {
            float4 cv = cg[q];
            float4 v0 = i0[q];
            float4 v1 = i1[q];
            s0 += v0.x * cv.x + v0.y * cv.y + v0.z * cv.z + v0.w * cv.w;
            s1 += v1.x * cv.x + v1.y * cv.y + v1.z * cv.z + v1.w * cv.w;
        }
        aws[n][kq] = s0;
        aws[n][kq + 16] = s1;
    }
    __syncthreads();

    // stable descending rank + dyn_K mask
    {
        int c = catc[b];
        int dynK = 32 - __clz(2 * c - 1);   // clip(ceil(log2(2c)),1,32) for c in [1,20]
        const int k = tid & 31;
        const int n1 = tid >> 5;
        #pragma unroll
        for (int h = 0; h < 2; ++h) {
            int n = n1 + 8 * h;
            float a = aws[n][k];
            int cnt = 0;
            #pragma unroll
            for (int j = 0; j < 32; ++j) {
                float aj = aws[n][j];
                cnt += (aj > a) || (aj == a && j < k);
            }
            maw[n][k] = (cnt < dynK) ? a : 0.0f;
        }
    }
    __syncthreads();

    // user[n][d] = sum_k maw[n][k] * ints[k][d]
    {
        const int dd = tid & 63;
        const int ng = tid >> 6;
        float4 acc4[4];
        #pragma unroll
        for (int nn = 0; nn < 4; ++nn) { acc4[nn].x = acc4[nn].y = acc4[nn].z = acc4[nn].w = 0.0f; }
        for (int k = 0; k < 32; ++k) {
            float4 iv = *(const float4*)&ints[k][4 * dd];
            #pragma unroll
            for (int nn = 0; nn < 4; ++nn) {
                float m = maw[4 * ng + nn][k];
                acc4[nn].x = fmaf(m, iv.x, acc4[nn].x);
                acc4[nn].y = fmaf(m, iv.y, acc4[nn].y);
                acc4[nn].z = fmaf(m, iv.z, acc4[nn].z);
                acc4[nn].w = fmaf(m, iv.w, acc4[nn].w);
            }
        }
        #pragma unroll
        for (int nn = 0; nn < 4; ++nn) {
            *(float4*)&out[((size_t)b * 16 + 4 * ng + nn) * 256 + 4 * dd] = acc4[nn];
        }
    }
}

extern "C" void kernel_launch(void* const* d_in, const int* in_sizes, int n_in,
                              void* d_out, int out_size, void* d_ws, size_t ws_size,
                              hipStream_t stream) {
    const float* hist = (const float*)d_in[0];
    const float* cand = (const float*)d_in[2];
    const int*   numi = (const int*)d_in[3];
    const int*   catc = (const int*)d_in[4];
    const float* W    = (const float*)d_in[5];
    const float* cc   = (const float*)d_in[6];
    float* out = (float*)d_out;
    float* logits = (float*)d_ws;                 // 26,214,400 B
    const size_t LOG_BYTES = 26214400;
    const size_t WF_BYTES = 262144;               // 8kt x 2spl x 16ct x 64 x 16B
    const size_t CF_BYTES = 32768;                // 8et x 2spl x 2ct x 64 x 16B
    char* fragBase = (ws_size >= LOG_BYTES + WF_BYTES + CF_BYTES)
                     ? ((char*)d_ws + LOG_BYTES)
                     : (char*)d_out;   // d_out fully rewritten by k_attn afterwards
    half8* Wf = (half8*)fragBase;
    half8* Cf = (half8*)(fragBase + WF_BYTES);

    k_prep<<<36, 256, 0, stream>>>(W, cc, Wf, Cf);
    k_proj_logits<<<1600, 256, 0, stream>>>(hist, Wf, Cf, logits);
    k_attn<<<2048, 256, 0, stream>>>(hist, cand, numi, catc, logits, out);
}